// Round 1
// baseline (92.977 us; speedup 1.0000x reference)
//
#include <hip/hip_runtime.h>

// QuantumLSTMCell, fused single-kernel version.
// Per row: u = W*x+b; joint = outer(u,h)/(|u||h|); psi = C*joint; p = psi^2;
// h_next[a] = sum_s p[4s+a]; out = sum_r z_r p_r.
// C (16x16, from 16 angles) is rebuilt redundantly per block in LDS (~16K FMA
// + 32 trig per thread, <0.5us chip-wide at 1024 blocks) so no workspace and
// no second kernel launch is needed. Folded: psi_r*|u||h| = x*(A_r.h)+(B_r.h).

#define ROWS_PER_BLOCK 1024  // 256 threads x 4 rows, lane-striped

__device__ __forceinline__ int ring_perm(int k) {
  // CNOT(0,1), CNOT(1,2), CNOT(2,3), CNOT(3,0) in sequence; wire 0 = MSB.
  int b0 = (k >> 3) & 1, b1 = (k >> 2) & 1, b2 = (k >> 1) & 1, b3 = k & 1;
  b1 ^= b0; b2 ^= b1; b3 ^= b2; b0 ^= b3;
  return (b0 << 3) | (b1 << 2) | (b2 << 1) | b3;
}

__global__ __launch_bounds__(256) void qlstm_fused(
    const float* __restrict__ x, const float4* __restrict__ h_prev,
    const float* __restrict__ W_in, const float* __restrict__ b_in,
    const float* __restrict__ U, const float* __restrict__ Ud,
    float4* __restrict__ h_next, float* __restrict__ outp, int B) {
  __shared__ float M[16][16];   // running product of layer unitaries
  __shared__ float Lm[16][16];  // current layer unitary
  __shared__ float4 sA[16];     // A[r][k] = sum_q W_q * C[r][4q+k]
  __shared__ float4 sB[16];     // Bm[r][k] = sum_q b_q * C[r][4q+k]
  __shared__ float sQ[3];       // |u|^2 = qa*x^2 + qb*x + qc

  const int t = threadIdx.x;

  // ---------- Phase 1: build constants (redundant per block) ----------
  {
    const int i = t >> 4, j = t & 15;
    const int pi = ring_perm(i);

    // weights order: U[0], U[1], Udagger[1], Udagger[0]
    float ang[4][4];
#pragma unroll
    for (int q = 0; q < 4; ++q) {
      ang[0][q] = U[q];
      ang[1][q] = U[4 + q];
      ang[2][q] = Ud[4 + q];
      ang[3][q] = Ud[q];
    }

    // layer 0: M = RING @ kron(RY(w0)..RY(w3))  (scatter through perm)
    {
      float kel = 1.f;
#pragma unroll
      for (int q = 0; q < 4; ++q) {
        float c = cosf(0.5f * ang[0][q]);
        float s = sinf(0.5f * ang[0][q]);
        int iq = (i >> (3 - q)) & 1, jq = (j >> (3 - q)) & 1;
        kel *= (iq == jq) ? c : (iq ? s : -s);
      }
      M[pi][j] = kel;
    }
    __syncthreads();

    for (int l = 1; l < 4; ++l) {
      float kel = 1.f;
#pragma unroll
      for (int q = 0; q < 4; ++q) {
        float c = cosf(0.5f * ang[l][q]);
        float s = sinf(0.5f * ang[l][q]);
        int iq = (i >> (3 - q)) & 1, jq = (j >> (3 - q)) & 1;
        kel *= (iq == jq) ? c : (iq ? s : -s);
      }
      Lm[pi][j] = kel;
      __syncthreads();
      float acc = 0.f;
#pragma unroll
      for (int k = 0; k < 16; ++k) acc += Lm[i][k] * M[k][j];
      __syncthreads();  // all reads of M done before overwrite
      M[i][j] = acc;
      __syncthreads();
    }

    if (t < 64) {
      const int r = t >> 2, k = t & 3;
      float a = 0.f, bb = 0.f;
#pragma unroll
      for (int q = 0; q < 4; ++q) {
        float c = M[r][4 * q + k];
        a = fmaf(W_in[q], c, a);
        bb = fmaf(b_in[q], c, bb);
      }
      ((float*)sA)[t] = a;   // t == r*4+k
      ((float*)sB)[t] = bb;
    }
    if (t == 0) {
      float qa = 0.f, qb = 0.f, qc = 0.f;
#pragma unroll
      for (int q = 0; q < 4; ++q) {
        qa = fmaf(W_in[q], W_in[q], qa);
        qb = fmaf(2.f * W_in[q], b_in[q], qb);
        qc = fmaf(b_in[q], b_in[q], qc);
      }
      sQ[0] = qa; sQ[1] = qb; sQ[2] = qc;
    }
    __syncthreads();
  }

  // ---------- Phase 2: 4 rows per thread, lane-striped (coalesced) ----------
  const int base = blockIdx.x * ROWS_PER_BLOCK + t;
  const float qa = sQ[0], qb = sQ[1], qc = sQ[2];

  float xv[4];
  float4 h[4];
  bool ok[4];
#pragma unroll
  for (int j = 0; j < 4; ++j) {
    const int row = base + j * 256;
    ok[j] = row < B;
    xv[j] = ok[j] ? x[row] : 0.f;
    h[j] = ok[j] ? h_prev[row] : make_float4(0.f, 0.f, 0.f, 0.f);
  }

  float inv2[4];
#pragma unroll
  for (int j = 0; j < 4; ++j) {
    float nh2 = fmaf(h[j].x, h[j].x,
                fmaf(h[j].y, h[j].y,
                fmaf(h[j].z, h[j].z, h[j].w * h[j].w)));
    float nu2 = fmaf(fmaf(qa, xv[j], qb), xv[j], qc);
    inv2[j] = __builtin_amdgcn_rcpf(nu2 * nh2);  // 1/(|u|^2 |h|^2), both > 0
  }

  float hn[4][4] = {};
  float po[4] = {0.f, 0.f, 0.f, 0.f};
#pragma unroll
  for (int r = 0; r < 16; ++r) {
    const float4 a = sA[r];   // ds_read_b128, uniform addr -> broadcast
    const float4 bm = sB[r];
#pragma unroll
    for (int j = 0; j < 4; ++j) {
      float ar = fmaf(a.x, h[j].x,
                 fmaf(a.y, h[j].y,
                 fmaf(a.z, h[j].z, a.w * h[j].w)));
      float br = fmaf(bm.x, h[j].x,
                 fmaf(bm.y, h[j].y,
                 fmaf(bm.z, h[j].z, bm.w * h[j].w)));
      float tr = fmaf(xv[j], ar, br);
      float s = tr * tr;
      hn[j][r & 3] += s;
      po[j] += ((r >> 2) & 1) ? -s : s;
    }
  }

#pragma unroll
  for (int j = 0; j < 4; ++j) {
    if (ok[j]) {
      const int row = base + j * 256;
      h_next[row] = make_float4(hn[j][0] * inv2[j], hn[j][1] * inv2[j],
                                hn[j][2] * inv2[j], hn[j][3] * inv2[j]);
      outp[row] = po[j] * inv2[j];
    }
  }
}

extern "C" void kernel_launch(void* const* d_in, const int* in_sizes, int n_in,
                              void* d_out, int out_size, void* d_ws, size_t ws_size,
                              hipStream_t stream) {
  const float* x  = (const float*)d_in[0];
  const float* h  = (const float*)d_in[1];
  const float* W  = (const float*)d_in[2];
  const float* bi = (const float*)d_in[3];
  const float* U  = (const float*)d_in[4];
  const float* Ud = (const float*)d_in[5];
  const int B = in_sizes[0];
  float* h_next = (float*)d_out;
  float* out1   = (float*)d_out + 4 * (size_t)B;

  const int grid = (B + ROWS_PER_BLOCK - 1) / ROWS_PER_BLOCK;
  qlstm_fused<<<grid, 256, 0, stream>>>(
      x, (const float4*)h, W, bi, U, Ud, (float4*)h_next, out1, B);
}